// Round 6
// baseline (130.584 us; speedup 1.0000x reference)
//
#include <hip/hip_runtime.h>
#include <stdint.h>

// Problem constants (reference: B=2, C=4, SPATIAL=(128,128,128), N_PTS=32, THR=0.5)
#define Bn 2
#define Cn 4
#define Sn (128 * 128 * 128)   // 2^21 voxels per (b,c)
#define NPTS 32
#define NBINS 1025             // probs in (0.5, 1] -> one binade; (bits-0x3F000000)>>13 in [0,1024]
#define THRf 0.5f
#define PB 4096                // voxels per block in the fused pass
#define BT 512                 // threads per fused block (8 waves; LDS 48.5KB -> 3 blk/CU = 24 waves/CU)
#define FCAP 2048              // LDS filtered-candidate cap in select_emit

__device__ __forceinline__ int bin_of_bits(unsigned int u) {
    return (int)((u - 0x3F000000u) >> 13);
}

// Softmax over the 4 classes at one voxel; mirrors jax.nn.softmax exactly
// (exp(x-max)/sum, sequential sum c=0..3). Only the argmax class can exceed 0.5.
__device__ __forceinline__ void softmax_argmax4(float l0, float l1, float l2, float l3,
                                                int* cm_out, float* p_out) {
    float m = fmaxf(fmaxf(l0, l1), fmaxf(l2, l3));
    float e0 = expf(l0 - m);
    float e1 = expf(l1 - m);
    float e2 = expf(l2 - m);
    float e3 = expf(l3 - m);
    float s = ((e0 + e1) + e2) + e3;
    float em = e0; int cm = 0;
    if (e1 > em) { em = e1; cm = 1; }
    if (e2 > em) { em = e2; cm = 2; }
    if (e3 > em) { em = e3; cm = 3; }
    *cm_out = cm;
    *p_out = em / s;
}

// Fused single-read pass. Round-5 lesson: per-lane same-address LDS atomics
// (ccount/cls_pos, ~1800/block) serialized the wave and fenced the load stream
// (VALUBusy 27%, 42 us). All appends are now wave-ballot aggregated: one lane-0
// LDS atomic per wave per step, lanes write at base+prefix.
__global__ __launch_bounds__(BT) void fused_kernel(const float* __restrict__ logits,
                                                   unsigned int* __restrict__ cnt,
                                                   uint2* __restrict__ cand,
                                                   int cap) {
    __shared__ unsigned int lh[Cn * NBINS];   // 16.4 KB per-class local radix hist
    __shared__ uint2 buf[PB];                 // 32 KB candidate cache (max 1/voxel)
    __shared__ unsigned int ccount;
    __shared__ unsigned int lcut[Cn];
    __shared__ unsigned int cls_cnt[Cn], cls_base[Cn], cls_pos[Cn];
    const int b = blockIdx.y;
    const int t = threadIdx.x;
    const int lane = t & 63;
    for (int j = t; j < Cn * NBINS; j += BT) lh[j] = 0u;
    if (t == 0) ccount = 0u;
    if (t < Cn) { lcut[t] = 0u; cls_cnt[t] = 0u; cls_pos[t] = 0u; }
    __syncthreads();

    // phase 1: stream voxels (float4 x 4 class streams), ballot-append candidates
    const float* base = logits + (size_t)b * Cn * Sn;
    const float4* s0 = (const float4*)base;
    const float4* s1 = (const float4*)(base + Sn);
    const float4* s2 = (const float4*)(base + 2 * Sn);
    const float4* s3 = (const float4*)(base + 3 * Sn);
    const int qs = blockIdx.x * (PB / 4);
    #pragma unroll
    for (int it = 0; it < PB / 4 / BT; ++it) {   // 2 iterations
        int q = qs + it * BT + t;
        float4 v0 = s0[q], v1 = s1[q], v2 = s2[q], v3 = s3[q];
        const float* a0 = &v0.x; const float* a1 = &v1.x;
        const float* a2 = &v2.x; const float* a3 = &v3.x;
        #pragma unroll
        for (int k = 0; k < 4; ++k) {
            int cm; float p;
            softmax_argmax4(a0[k], a1[k], a2[k], a3[k], &cm, &p);
            bool pass = p > THRf;
            unsigned int ub = __float_as_uint(p);
            if (pass) atomicAdd(&lh[cm * NBINS + bin_of_bits(ub)], 1u);
            unsigned long long mk = __ballot(pass);
            if (mk) {  // wave-uniform
                unsigned int bs = 0;
                if (lane == 0) bs = atomicAdd(&ccount, (unsigned int)__popcll(mk));
                bs = __shfl(bs, 0, 64);
                if (pass) {
                    unsigned int pfx = (unsigned int)__popcll(mk & ((1ull << lane) - 1ull));
                    // idx fits in 21 bits (Sn = 2^21); class in bits 21-22
                    buf[bs + pfx] = make_uint2(ub, (unsigned int)(q * 4 + k) |
                                                   ((unsigned int)cm << 21));
                }
            }
        }
    }
    __syncthreads();

    // phase 2: wave w (w<4) computes local cutoff for class w (64 lanes x 17 bins >= 1025).
    // Entries below the local cutoff have >=32 strictly-greater local entries ->
    // global rank >= 32 -> safe to drop. Union over blocks is a superset of top-32.
    {
        const int wave = t >> 6;
        if (wave < Cn) {
            const unsigned int* h = &lh[wave * NBINS];
            const int lo = lane * 17;
            unsigned int cs = 0;
            #pragma unroll
            for (int k = 0; k < 17; ++k) {
                int bin = lo + k;
                if (bin < NBINS) cs += h[bin];
            }
            unsigned int S = cs;  // inclusive suffix sum over lanes
            #pragma unroll
            for (int off = 1; off < 64; off <<= 1) {
                unsigned int v = __shfl_down(S, off, 64);
                if (lane + off < 64) S += v;
            }
            unsigned int suf = S - cs;
            if (S >= NPTS && suf < NPTS) {
                unsigned int acc = suf;
                int hi = min(lo + 16, NBINS - 1);
                for (int bin = hi; bin >= lo; --bin) {
                    acc += h[bin];
                    if (acc >= NPTS) { lcut[wave] = (unsigned int)bin; break; }
                }
            }
            // class total < 32: no lane fires, lcut stays 0 (emit all)
        }
    }
    __syncthreads();

    // phase 3a: per-class passing counts (ballot, lane-0 atomics only)
    const unsigned int n = ccount;
    for (unsigned int j0 = 0; j0 < n; j0 += BT) {
        unsigned int j = j0 + t;
        bool v = j < n;
        uint2 e = v ? buf[j] : make_uint2(0u, 0u);
        unsigned int cm = e.y >> 21;
        bool pass = v && ((unsigned int)bin_of_bits(e.x) >= lcut[cm]);
        #pragma unroll
        for (int c = 0; c < Cn; ++c) {
            unsigned long long mk = __ballot(pass && cm == (unsigned int)c);
            if (mk && lane == 0) atomicAdd(&cls_cnt[c], (unsigned int)__popcll(mk));
        }
    }
    __syncthreads();
    // phase 3b: one global reservation per (block, class)
    if (t < Cn && cls_cnt[t] > 0)
        cls_base[t] = atomicAdd(&cnt[b * Cn + t], cls_cnt[t]);
    __syncthreads();
    // phase 3c: ballot-aggregated writes at reserved offsets (order irrelevant —
    // select_emit re-ranks exactly)
    for (unsigned int j0 = 0; j0 < n; j0 += BT) {
        unsigned int j = j0 + t;
        bool v = j < n;
        uint2 e = v ? buf[j] : make_uint2(0u, 0u);
        unsigned int cm = e.y >> 21;
        bool pass = v && ((unsigned int)bin_of_bits(e.x) >= lcut[cm]);
        #pragma unroll
        for (int c = 0; c < Cn; ++c) {
            unsigned long long mk = __ballot(pass && cm == (unsigned int)c);
            if (mk) {
                unsigned int wb = 0;
                if (lane == 0) wb = atomicAdd(&cls_pos[c], (unsigned int)__popcll(mk));
                wb = __shfl(wb, 0, 64);
                if (pass && cm == (unsigned int)c) {
                    unsigned int pfx = (unsigned int)__popcll(mk & ((1ull << lane) - 1ull));
                    unsigned int pos = cls_base[c] + wb + pfx;
                    if (pos < (unsigned int)cap)
                        cand[(size_t)(b * Cn + c) * cap + pos] =
                            make_uint2(e.x, e.y & 0x1FFFFFu);
                }
            }
        }
    }
}

// Exact top-32 per (b,c) (one 1024-thread block per (b,c)), then the LAST
// finishing block of each batch (device done-counter + threadfence) performs the
// cross-class compaction/emit — saves a separate emit launch.
// Correctness of selection: bins strictly above the superset-derived cutoff are
// complete in the superset (every such entry has global rank < 32, and all
// rank<32 entries survive every block's local cutoff), so ranking within the
// filtered set is exact for the top-32. validn = min(n,32) is exact.
__global__ __launch_bounds__(1024) void select_emit(const unsigned int* __restrict__ cnt,
                                                    const uint2* __restrict__ cand,
                                                    int cap,
                                                    unsigned int* __restrict__ validn,
                                                    uint2* __restrict__ topk,
                                                    unsigned int* __restrict__ done,
                                                    int* __restrict__ out) {
    __shared__ unsigned int lh[NBINS];
    __shared__ uint2 fbuf[FCAP];
    __shared__ unsigned int s_m, s_T, s_old;
    const int bc = blockIdx.x, t = threadIdx.x;
    const int b = bc >> 2;
    const int n = min((int)cnt[bc], cap);
    for (int j = t; j < NBINS; j += 1024) lh[j] = 0u;
    if (t == 0) { s_m = 0u; s_T = 0u; }
    __syncthreads();
    const uint2* src = cand + (size_t)bc * cap;
    for (int j = t; j < n; j += 1024)
        atomicAdd(&lh[bin_of_bits(src[j].x)], 1u);
    __syncthreads();
    if (t < 64) {  // wave 0: exact global cutoff scan
        const int lane = t;
        const int lo = lane * 17;
        unsigned int cs = 0;
        #pragma unroll
        for (int k = 0; k < 17; ++k) {
            int bin = lo + k;
            if (bin < NBINS) cs += lh[bin];
        }
        unsigned int S = cs;
        #pragma unroll
        for (int off = 1; off < 64; off <<= 1) {
            unsigned int v = __shfl_down(S, off, 64);
            if (lane + off < 64) S += v;
        }
        unsigned int suf = S - cs;
        if (S >= NPTS && suf < NPTS) {
            unsigned int acc = suf;
            int hi = min(lo + 16, NBINS - 1);
            for (int bin = hi; bin >= lo; --bin) {
                acc += lh[bin];
                if (acc >= NPTS) { s_T = (unsigned int)bin; break; }
            }
        }
    }
    __syncthreads();
    const unsigned int T = s_T;
    for (int j = t; j < n; j += 1024) {
        uint2 e = src[j];
        if ((unsigned int)bin_of_bits(e.x) >= T) {
            unsigned int pos = atomicAdd(&s_m, 1u);   // ~40 total, cheap
            if (pos < FCAP) fbuf[pos] = e;
        }
    }
    __syncthreads();
    const int m = min((int)s_m, FCAP);
    const int vn = min(n, NPTS);
    if (t == 0) validn[bc] = (unsigned int)vn;
    for (int i = t; i < m; i += 1024) {   // exact rank, jax tie-break (lower idx wins)
        uint2 e = fbuf[i];
        int rank = 0;
        for (int j = 0; j < m; ++j) {
            uint2 o = fbuf[j];
            rank += (int)((o.x > e.x) || (o.x == e.x && o.y < e.y));
        }
        if (rank < vn) topk[bc * NPTS + rank] = e;
    }

    // epilogue: last finishing block of this batch emits
    __threadfence();
    __syncthreads();
    if (t == 0) s_old = atomicAdd(&done[b], 1u);
    __syncthreads();
    if (s_old == 3u) {
        __threadfence();  // acquire: see other blocks' topk/validn
        __shared__ int pre[Cn + 1];
        if (t == 0) {
            int acc = 0;
            for (int oc = 0; oc < Cn; ++oc) {
                pre[oc] = acc;
                acc += (int)validn[b * Cn + ((oc + 1) & 3)];  // order [1,2,3,0]
            }
            pre[Cn] = acc;
        }
        __syncthreads();
        if (t < Cn * NPTS) {  // 128 output slots for batch b
            const int j = t;
            int label = -1, z = 0, y = 0, x = 0;
            if (j < pre[Cn]) {
                int oc = 0;
                while (j >= pre[oc + 1]) ++oc;
                int c = (oc + 1) & 3;
                int r = j - pre[oc];
                uint2 e = topk[(b * Cn + c) * NPTS + r];
                int idx = (int)e.y;
                z = idx >> 14;          // idx / (128*128)
                y = (idx >> 7) & 127;   // (idx / 128) % 128
                x = idx & 127;          // idx % 128
                label = c;
            }
            int* coords = out;                       // 2*128*3 = 768 ints
            int* labels = out + Bn * Cn * NPTS * 3;  // then 2*128 = 256 ints
            int bo = b * Cn * NPTS + j;
            coords[bo * 3 + 0] = z;
            coords[bo * 3 + 1] = y;
            coords[bo * 3 + 2] = x;
            labels[bo] = label;
        }
    }
}

extern "C" void kernel_launch(void* const* d_in, const int* in_sizes, int n_in,
                              void* d_out, int out_size, void* d_ws, size_t ws_size,
                              hipStream_t stream) {
    const float* logits = (const float*)d_in[0];
    int* out = (int*)d_out;

    // Workspace layout
    unsigned int* cnt = (unsigned int*)d_ws;             // 8 u32  @0
    unsigned int* done = cnt + Bn * Cn;                  // 2 u32  @32
    unsigned int* validn = done + Bn;                    // 8 u32  @40
    uint2* topk = (uint2*)(validn + Bn * Cn);            // 8*32 uint2 @72 (8-aligned)
    uint2* cand = topk + Bn * Cn * NPTS;                 // 8 * cap uint2
    size_t fixed = (size_t)((char*)cand - (char*)d_ws);
    int cap = (int)((ws_size - fixed) / (Bn * Cn * sizeof(uint2)));
    if (cap > (1 << 18)) cap = 1 << 18;   // 256k entries/bc >> the ~17k expected
    if (cap < 4096) cap = 4096;

    // Zero cnt (8) + done (2) counters only
    hipMemsetAsync(cnt, 0, (Bn * Cn + Bn) * sizeof(unsigned int), stream);

    dim3 grid(Sn / PB, Bn);   // (512, 2)
    fused_kernel<<<grid, BT, 0, stream>>>(logits, cnt, cand, cap);
    select_emit<<<Bn * Cn, 1024, 0, stream>>>(cnt, cand, cap, validn, topk, done, out);
}

// Round 7
// 125.046 us; speedup vs baseline: 1.0443x; 1.0443x over previous
//
#include <hip/hip_runtime.h>
#include <stdint.h>

// Problem constants (reference: B=2, C=4, SPATIAL=(128,128,128), N_PTS=32, THR=0.5)
#define Bn 2
#define Cn 4
#define Sn (128 * 128 * 128)   // 2^21 voxels per (b,c)
#define NPTS 32
#define NBINS 1025             // probs in (0.5, 1] -> one binade; (bits-0x3F000000)>>13 in [0,1024]
#define THRf 0.5f
#define PB 4096                // voxels per block in the fused pass
#define BT 512                 // threads/block: 8 waves; LDS ~32.9KB -> 4 blk/CU = 32 waves/CU
#define FCAP 2048              // LDS filtered-candidate cap in select_emit

__device__ __forceinline__ int bin_of_bits(unsigned int u) {
    return (int)((u - 0x3F000000u) >> 13);
}

// Softmax over the 4 classes at one voxel; mirrors jax.nn.softmax exactly
// (exp(x-max)/sum, sequential sum c=0..3). Only the argmax class can exceed 0.5.
__device__ __forceinline__ void softmax_argmax4(float l0, float l1, float l2, float l3,
                                                int* cm_out, float* p_out) {
    float m = fmaxf(fmaxf(l0, l1), fmaxf(l2, l3));
    float e0 = expf(l0 - m);
    float e1 = expf(l1 - m);
    float e2 = expf(l2 - m);
    float e3 = expf(l3 - m);
    float s = ((e0 + e1) + e2) + e3;
    float em = e0; int cm = 0;
    if (e1 > em) { em = e1; cm = 1; }
    if (e2 > em) { em = e2; cm = 2; }
    if (e3 > em) { em = e3; cm = 3; }
    *cm_out = cm;
    *p_out = em / s;
}

// Fused single-read pass. Rounds 5/6 lesson: both per-lane and ballot-aggregated
// RETURNING LDS atomics per candidate (~1800/block) gave identical 42 us — the
// wait-for-atomic-result + dependent buf write on the hot path was the limiter.
// Now phase 1 has ZERO cross-lane ops: each voxel's result goes to buf[slot] at
// its natural position, packed u32 = (p_off<<2)|class (0 = invalid; p>0.5 =>
// p_off>=1 => nonzero), one ds_write_b128 per thread per iteration.
__global__ __launch_bounds__(BT) void fused_kernel(const float* __restrict__ logits,
                                                   unsigned int* __restrict__ cnt,
                                                   uint2* __restrict__ cand,
                                                   int cap) {
    __shared__ unsigned int lh[Cn * NBINS];   // 16.4 KB per-class local radix hist
    __shared__ unsigned int buf[PB];          // 16 KB slot-addressed packed candidates
    __shared__ unsigned int lcut[Cn], cls_cnt[Cn], cls_base[Cn], cls_pos[Cn];
    const int b = blockIdx.y;
    const int t = threadIdx.x;
    const int lane = t & 63;
    for (int j = t; j < Cn * NBINS; j += BT) lh[j] = 0u;
    if (t < Cn) { lcut[t] = 0u; cls_cnt[t] = 0u; cls_pos[t] = 0u; }
    __syncthreads();

    // phase 1: stream voxels (float4 x 4 class streams); no atomics-with-return
    const float* base = logits + (size_t)b * Cn * Sn;
    const float4* s0 = (const float4*)base;
    const float4* s1 = (const float4*)(base + Sn);
    const float4* s2 = (const float4*)(base + 2 * Sn);
    const float4* s3 = (const float4*)(base + 3 * Sn);
    const int qs = blockIdx.x * (PB / 4);
    #pragma unroll
    for (int it = 0; it < PB / 4 / BT; ++it) {   // 2 iterations
        int q = qs + it * BT + t;
        float4 v0 = s0[q], v1 = s1[q], v2 = s2[q], v3 = s3[q];
        const float* a0 = &v0.x; const float* a1 = &v1.x;
        const float* a2 = &v2.x; const float* a3 = &v3.x;
        uint4 pk;
        unsigned int* pkv = (unsigned int*)&pk;
        #pragma unroll
        for (int k = 0; k < 4; ++k) {
            int cm; float p;
            softmax_argmax4(a0[k], a1[k], a2[k], a3[k], &cm, &p);
            unsigned int pv = 0u;
            if (p > THRf) {
                unsigned int off = __float_as_uint(p) - 0x3F000000u;  // 1..0x800000
                atomicAdd(&lh[cm * NBINS + (int)(off >> 13)], 1u);    // no-return ds_add
                pv = (off << 2) | (unsigned int)cm;                   // 26 bits, nonzero
            }
            pkv[k] = pv;
        }
        ((uint4*)buf)[it * BT + t] = pk;   // slots (it*BT+t)*4 .. +3, conflict-free b128
    }
    __syncthreads();

    // phase 2: wave w (w<4) computes local cutoff for class w (64 lanes x 17 bins >= 1025).
    // Entries below the local cutoff have >=32 strictly-greater local entries ->
    // global rank >= 32 -> safe to drop. Union over blocks is a superset of top-32.
    // The break-time acc = count of entries in bins >= lcut = exact emit count (cls_cnt).
    {
        const int wave = t >> 6;
        if (wave < Cn) {
            const unsigned int* h = &lh[wave * NBINS];
            const int lo = lane * 17;
            unsigned int cs = 0;
            #pragma unroll
            for (int k = 0; k < 17; ++k) {
                int bin = lo + k;
                if (bin < NBINS) cs += h[bin];
            }
            unsigned int S = cs;  // inclusive suffix sum over lanes [lane..63]
            #pragma unroll
            for (int off = 1; off < 64; off <<= 1) {
                unsigned int v = __shfl_down(S, off, 64);
                if (lane + off < 64) S += v;
            }
            unsigned int suf = S - cs;
            if (S >= NPTS && suf < NPTS) {   // exactly one lane (when total >= 32)
                unsigned int acc = suf;
                int hi = min(lo + 16, NBINS - 1);
                for (int bin = hi; bin >= lo; --bin) {
                    acc += h[bin];
                    if (acc >= NPTS) {
                        lcut[wave] = (unsigned int)bin;
                        cls_cnt[wave] = acc;
                        break;
                    }
                }
            }
            if (lane == 0 && S < NPTS) cls_cnt[wave] = S;  // total<32: lcut=0, emit all
        }
    }
    __syncthreads();

    // reservation: one global atomic per (block, class)
    if (t < Cn && cls_cnt[t] > 0)
        cls_base[t] = atomicAdd(&cnt[b * Cn + t], cls_cnt[t]);
    __syncthreads();

    // phase 3: scan 8 slots/thread (2 ds_read_b128), ballot-append ~130 survivors
    #pragma unroll
    for (int g = 0; g < PB / 4 / BT; ++g) {
        uint4 pk = ((const uint4*)buf)[g * BT + t];
        const unsigned int* pkv = (const unsigned int*)&pk;
        #pragma unroll
        for (int k = 0; k < 4; ++k) {
            unsigned int pv = pkv[k];
            unsigned int cm = pv & 3u;
            bool pass = (pv != 0u) && ((pv >> 15) >= lcut[cm]);  // pv>>15 == p_off>>13 == bin
            if (__ballot(pass)) {
                #pragma unroll
                for (int c = 0; c < Cn; ++c) {
                    unsigned long long mk = __ballot(pass && cm == (unsigned int)c);
                    if (mk) {
                        unsigned int wb = 0;
                        if (lane == 0) wb = atomicAdd(&cls_pos[c], (unsigned int)__popcll(mk));
                        wb = __shfl(wb, 0, 64);
                        if (pass && cm == (unsigned int)c) {
                            unsigned int pfx = (unsigned int)__popcll(mk & ((1ull << lane) - 1ull));
                            unsigned int pos = cls_base[c] + wb + pfx;
                            if (pos < (unsigned int)cap) {
                                unsigned int idx = (unsigned int)(blockIdx.x * PB +
                                                                  (g * BT + t) * 4 + k);
                                cand[(size_t)(b * Cn + c) * cap + pos] =
                                    make_uint2(0x3F000000u + (pv >> 2), idx);
                            }
                        }
                    }
                }
            }
        }
    }
}

// Exact top-32 per (b,c) (one 1024-thread block per (b,c)), then the LAST
// finishing block of each batch (device done-counter + threadfence) performs the
// cross-class compaction/emit.
// Correctness: bins strictly above the superset-derived cutoff are complete in
// the superset (every such entry has global rank < 32, and all rank<32 entries
// survive every block's local cutoff), so ranking within the filtered set is
// exact for the top-32. validn = min(n,32) is exact.
__global__ __launch_bounds__(1024) void select_emit(const unsigned int* __restrict__ cnt,
                                                    const uint2* __restrict__ cand,
                                                    int cap,
                                                    unsigned int* __restrict__ validn,
                                                    uint2* __restrict__ topk,
                                                    unsigned int* __restrict__ done,
                                                    int* __restrict__ out) {
    __shared__ unsigned int lh[NBINS];
    __shared__ uint2 fbuf[FCAP];
    __shared__ unsigned int s_m, s_T, s_old;
    const int bc = blockIdx.x, t = threadIdx.x;
    const int b = bc >> 2;
    const int n = min((int)cnt[bc], cap);
    for (int j = t; j < NBINS; j += 1024) lh[j] = 0u;
    if (t == 0) { s_m = 0u; s_T = 0u; }
    __syncthreads();
    const uint2* src = cand + (size_t)bc * cap;
    for (int j = t; j < n; j += 1024)
        atomicAdd(&lh[bin_of_bits(src[j].x)], 1u);
    __syncthreads();
    if (t < 64) {  // wave 0: exact global cutoff scan
        const int lane = t;
        const int lo = lane * 17;
        unsigned int cs = 0;
        #pragma unroll
        for (int k = 0; k < 17; ++k) {
            int bin = lo + k;
            if (bin < NBINS) cs += lh[bin];
        }
        unsigned int S = cs;
        #pragma unroll
        for (int off = 1; off < 64; off <<= 1) {
            unsigned int v = __shfl_down(S, off, 64);
            if (lane + off < 64) S += v;
        }
        unsigned int suf = S - cs;
        if (S >= NPTS && suf < NPTS) {
            unsigned int acc = suf;
            int hi = min(lo + 16, NBINS - 1);
            for (int bin = hi; bin >= lo; --bin) {
                acc += lh[bin];
                if (acc >= NPTS) { s_T = (unsigned int)bin; break; }
            }
        }
    }
    __syncthreads();
    const unsigned int T = s_T;
    for (int j = t; j < n; j += 1024) {
        uint2 e = src[j];
        if ((unsigned int)bin_of_bits(e.x) >= T) {
            unsigned int pos = atomicAdd(&s_m, 1u);   // ~40 total, cheap
            if (pos < FCAP) fbuf[pos] = e;
        }
    }
    __syncthreads();
    const int m = min((int)s_m, FCAP);
    const int vn = min(n, NPTS);
    if (t == 0) validn[bc] = (unsigned int)vn;
    for (int i = t; i < m; i += 1024) {   // exact rank, jax tie-break (lower idx wins)
        uint2 e = fbuf[i];
        int rank = 0;
        for (int j = 0; j < m; ++j) {
            uint2 o = fbuf[j];
            rank += (int)((o.x > e.x) || (o.x == e.x && o.y < e.y));
        }
        if (rank < vn) topk[bc * NPTS + rank] = e;
    }

    // epilogue: last finishing block of this batch emits
    __threadfence();
    __syncthreads();
    if (t == 0) s_old = atomicAdd(&done[b], 1u);
    __syncthreads();
    if (s_old == 3u) {
        __threadfence();  // acquire: see other blocks' topk/validn
        __shared__ int pre[Cn + 1];
        if (t == 0) {
            int acc = 0;
            for (int oc = 0; oc < Cn; ++oc) {
                pre[oc] = acc;
                acc += (int)validn[b * Cn + ((oc + 1) & 3)];  // order [1,2,3,0]
            }
            pre[Cn] = acc;
        }
        __syncthreads();
        if (t < Cn * NPTS) {  // 128 output slots for batch b
            const int j = t;
            int label = -1, z = 0, y = 0, x = 0;
            if (j < pre[Cn]) {
                int oc = 0;
                while (j >= pre[oc + 1]) ++oc;
                int c = (oc + 1) & 3;
                int r = j - pre[oc];
                uint2 e = topk[(b * Cn + c) * NPTS + r];
                int idx = (int)e.y;
                z = idx >> 14;          // idx / (128*128)
                y = (idx >> 7) & 127;   // (idx / 128) % 128
                x = idx & 127;          // idx % 128
                label = c;
            }
            int* coords = out;                       // 2*128*3 = 768 ints
            int* labels = out + Bn * Cn * NPTS * 3;  // then 2*128 = 256 ints
            int bo = b * Cn * NPTS + j;
            coords[bo * 3 + 0] = z;
            coords[bo * 3 + 1] = y;
            coords[bo * 3 + 2] = x;
            labels[bo] = label;
        }
    }
}

extern "C" void kernel_launch(void* const* d_in, const int* in_sizes, int n_in,
                              void* d_out, int out_size, void* d_ws, size_t ws_size,
                              hipStream_t stream) {
    const float* logits = (const float*)d_in[0];
    int* out = (int*)d_out;

    // Workspace layout
    unsigned int* cnt = (unsigned int*)d_ws;             // 8 u32  @0
    unsigned int* done = cnt + Bn * Cn;                  // 2 u32  @32
    unsigned int* validn = done + Bn;                    // 8 u32  @40
    uint2* topk = (uint2*)(validn + Bn * Cn);            // 8*32 uint2 @72 (8-aligned)
    uint2* cand = topk + Bn * Cn * NPTS;                 // 8 * cap uint2
    size_t fixed = (size_t)((char*)cand - (char*)d_ws);
    int cap = (int)((ws_size - fixed) / (Bn * Cn * sizeof(uint2)));
    if (cap > (1 << 18)) cap = 1 << 18;   // 256k entries/bc >> the ~18k expected
    if (cap < 4096) cap = 4096;

    // Zero cnt (8) + done (2) counters only
    hipMemsetAsync(cnt, 0, (Bn * Cn + Bn) * sizeof(unsigned int), stream);

    dim3 grid(Sn / PB, Bn);   // (512, 2) = 1024 blocks, fully co-resident at 4 blk/CU
    fused_kernel<<<grid, BT, 0, stream>>>(logits, cnt, cand, cap);
    select_emit<<<Bn * Cn, 1024, 0, stream>>>(cnt, cand, cap, validn, topk, done, out);
}

// Round 8
// 120.149 us; speedup vs baseline: 1.0869x; 1.0408x over previous
//
#include <hip/hip_runtime.h>
#include <stdint.h>

// Problem constants (reference: B=2, C=4, SPATIAL=(128,128,128), N_PTS=32, THR=0.5)
#define Bn 2
#define Cn 4
#define Sn (128 * 128 * 128)   // 2^21 voxels per (b,c)
#define NPTS 32
#define NBINS 1025             // probs in (0.5, 1] -> one binade; (bits-0x3F000000)>>13 in [0,1024]
#define THRf 0.5f
#define PB 4096                // voxels per block in the fused pass
#define BT 512                 // threads/block: 8 waves; LDS 16.5KB -> 4 blk/CU = 32 waves/CU
#define FCAP 2048              // LDS filtered-candidate cap in select_emit

__device__ __forceinline__ int bin_of_bits(unsigned int u) {
    return (int)((u - 0x3F000000u) >> 13);
}

// Softmax over the 4 classes at one voxel; mirrors jax.nn.softmax exactly
// (exp(x-max)/sum, sequential sum c=0..3). Only the argmax class can exceed 0.5.
__device__ __forceinline__ void softmax_argmax4(float l0, float l1, float l2, float l3,
                                                int* cm_out, float* p_out) {
    float m = fmaxf(fmaxf(l0, l1), fmaxf(l2, l3));
    float e0 = expf(l0 - m);
    float e1 = expf(l1 - m);
    float e2 = expf(l2 - m);
    float e3 = expf(l3 - m);
    float s = ((e0 + e1) + e2) + e3;
    float em = e0; int cm = 0;
    if (e1 > em) { em = e1; cm = 1; }
    if (e2 > em) { em = e2; cm = 2; }
    if (e3 > em) { em = e3; cm = 3; }
    *cm_out = cm;
    *p_out = em / s;
}

// Fused single-read pass, register-resident candidates.
// R7 lesson: the LDS slot-buffer round-trip + 32 ballots/thread in phase 3 were
// overhead sized for 1800 appends applied to ~130 survivors. Now packed results
// stay in the producing thread's registers (8 x u32), and survivors use a plain
// returning LDS atomic (~130/block, ~2 per wave-step — negligible serialization).
// Packed u32 = (p_off<<2)|class, 0 = invalid (p>0.5 => p_off>=1 => nonzero).
__global__ __launch_bounds__(BT) void fused_kernel(const float* __restrict__ logits,
                                                   unsigned int* __restrict__ cnt,
                                                   uint2* __restrict__ cand,
                                                   int cap) {
    __shared__ unsigned int lh[Cn * NBINS];   // 16.4 KB per-class local radix hist
    __shared__ unsigned int lcut[Cn], cls_cnt[Cn], cls_base[Cn], cls_pos[Cn];
    const int b = blockIdx.y;
    const int t = threadIdx.x;
    const int lane = t & 63;
    for (int j = t; j < Cn * NBINS; j += BT) lh[j] = 0u;
    if (t < Cn) { lcut[t] = 0u; cls_cnt[t] = 0u; cls_pos[t] = 0u; }
    __syncthreads();

    // phase 1: stream voxels (float4 x 4 class streams); results stay in registers
    const float* base = logits + (size_t)b * Cn * Sn;
    const float4* s0 = (const float4*)base;
    const float4* s1 = (const float4*)(base + Sn);
    const float4* s2 = (const float4*)(base + 2 * Sn);
    const float4* s3 = (const float4*)(base + 3 * Sn);
    const int qs = blockIdx.x * (PB / 4);
    unsigned int pk[PB / BT];   // 8 packed results per thread
    #pragma unroll
    for (int it = 0; it < PB / 4 / BT; ++it) {   // 2 iterations
        int q = qs + it * BT + t;
        float4 v0 = s0[q], v1 = s1[q], v2 = s2[q], v3 = s3[q];
        const float* a0 = &v0.x; const float* a1 = &v1.x;
        const float* a2 = &v2.x; const float* a3 = &v3.x;
        #pragma unroll
        for (int k = 0; k < 4; ++k) {
            int cm; float p;
            softmax_argmax4(a0[k], a1[k], a2[k], a3[k], &cm, &p);
            unsigned int pv = 0u;
            if (p > THRf) {
                unsigned int off = __float_as_uint(p) - 0x3F000000u;  // 1..0x800000
                atomicAdd(&lh[cm * NBINS + (int)(off >> 13)], 1u);    // no-return ds_add
                pv = (off << 2) | (unsigned int)cm;                   // 26 bits, nonzero
            }
            pk[it * 4 + k] = pv;
        }
    }
    __syncthreads();

    // phase 2: wave w (w<4) computes local cutoff for class w (64 lanes x 17 bins >= 1025).
    // Entries below the local cutoff have >=32 strictly-greater local entries ->
    // global rank >= 32 -> safe to drop. Union over blocks is a superset of top-32.
    // The break-time acc = count of entries in bins >= lcut = exact emit count.
    {
        const int wave = t >> 6;
        if (wave < Cn) {
            const unsigned int* h = &lh[wave * NBINS];
            const int lo = lane * 17;
            unsigned int cs = 0;
            #pragma unroll
            for (int k = 0; k < 17; ++k) {
                int bin = lo + k;
                if (bin < NBINS) cs += h[bin];
            }
            unsigned int S = cs;  // inclusive suffix sum over lanes [lane..63]
            #pragma unroll
            for (int off = 1; off < 64; off <<= 1) {
                unsigned int v = __shfl_down(S, off, 64);
                if (lane + off < 64) S += v;
            }
            unsigned int suf = S - cs;
            if (S >= NPTS && suf < NPTS) {   // exactly one lane (when total >= 32)
                unsigned int acc = suf;
                int hi = min(lo + 16, NBINS - 1);
                for (int bin = hi; bin >= lo; --bin) {
                    acc += h[bin];
                    if (acc >= NPTS) {
                        lcut[wave] = (unsigned int)bin;
                        cls_cnt[wave] = acc;
                        break;
                    }
                }
            }
            if (lane == 0 && S < NPTS) cls_cnt[wave] = S;  // total<32: lcut=0, emit all
        }
    }
    __syncthreads();

    // reservation: one global atomic per (block, class)
    if (t < Cn && cls_cnt[t] > 0)
        cls_base[t] = atomicAdd(&cnt[b * Cn + t], cls_cnt[t]);
    __syncthreads();

    // phase 3: emit survivors straight from registers (~130/block total)
    #pragma unroll
    for (int j = 0; j < PB / BT; ++j) {
        unsigned int pv = pk[j];
        if (pv != 0u) {
            unsigned int cm = pv & 3u;
            if ((pv >> 15) >= lcut[cm]) {   // pv>>15 == p_off>>13 == bin
                unsigned int pos = cls_base[cm] + atomicAdd(&cls_pos[cm], 1u);
                if (pos < (unsigned int)cap) {
                    int it = j >> 2, k = j & 3;
                    unsigned int idx = (unsigned int)((qs + it * BT + t) * 4 + k);
                    cand[(size_t)(b * Cn + cm) * cap + pos] =
                        make_uint2(0x3F000000u + (pv >> 2), idx);
                }
            }
        }
    }
}

// Exact top-32 per (b,c) (one 1024-thread block per (b,c)), then the LAST
// finishing block of each batch (device done-counter + threadfence) performs the
// cross-class compaction/emit.
// Correctness: bins strictly above the superset-derived cutoff are complete in
// the superset (every such entry has global rank < 32, and all rank<32 entries
// survive every block's local cutoff), so ranking within the filtered set is
// exact for the top-32. validn = min(n,32) is exact.
__global__ __launch_bounds__(1024) void select_emit(const unsigned int* __restrict__ cnt,
                                                    const uint2* __restrict__ cand,
                                                    int cap,
                                                    unsigned int* __restrict__ validn,
                                                    uint2* __restrict__ topk,
                                                    unsigned int* __restrict__ done,
                                                    int* __restrict__ out) {
    __shared__ unsigned int lh[NBINS];
    __shared__ uint2 fbuf[FCAP];
    __shared__ unsigned int s_m, s_T, s_old;
    const int bc = blockIdx.x, t = threadIdx.x;
    const int b = bc >> 2;
    const int n = min((int)cnt[bc], cap);
    for (int j = t; j < NBINS; j += 1024) lh[j] = 0u;
    if (t == 0) { s_m = 0u; s_T = 0u; }
    __syncthreads();
    const uint2* src = cand + (size_t)bc * cap;
    for (int j = t; j < n; j += 1024)
        atomicAdd(&lh[bin_of_bits(src[j].x)], 1u);
    __syncthreads();
    if (t < 64) {  // wave 0: exact global cutoff scan
        const int lane = t;
        const int lo = lane * 17;
        unsigned int cs = 0;
        #pragma unroll
        for (int k = 0; k < 17; ++k) {
            int bin = lo + k;
            if (bin < NBINS) cs += lh[bin];
        }
        unsigned int S = cs;
        #pragma unroll
        for (int off = 1; off < 64; off <<= 1) {
            unsigned int v = __shfl_down(S, off, 64);
            if (lane + off < 64) S += v;
        }
        unsigned int suf = S - cs;
        if (S >= NPTS && suf < NPTS) {
            unsigned int acc = suf;
            int hi = min(lo + 16, NBINS - 1);
            for (int bin = hi; bin >= lo; --bin) {
                acc += lh[bin];
                if (acc >= NPTS) { s_T = (unsigned int)bin; break; }
            }
        }
    }
    __syncthreads();
    const unsigned int T = s_T;
    for (int j = t; j < n; j += 1024) {
        uint2 e = src[j];
        if ((unsigned int)bin_of_bits(e.x) >= T) {
            unsigned int pos = atomicAdd(&s_m, 1u);   // ~40 total, cheap
            if (pos < FCAP) fbuf[pos] = e;
        }
    }
    __syncthreads();
    const int m = min((int)s_m, FCAP);
    const int vn = min(n, NPTS);
    if (t == 0) validn[bc] = (unsigned int)vn;
    for (int i = t; i < m; i += 1024) {   // exact rank, jax tie-break (lower idx wins)
        uint2 e = fbuf[i];
        int rank = 0;
        for (int j = 0; j < m; ++j) {
            uint2 o = fbuf[j];
            rank += (int)((o.x > e.x) || (o.x == e.x && o.y < e.y));
        }
        if (rank < vn) topk[bc * NPTS + rank] = e;
    }

    // epilogue: last finishing block of this batch emits
    __threadfence();
    __syncthreads();
    if (t == 0) s_old = atomicAdd(&done[b], 1u);
    __syncthreads();
    if (s_old == 3u) {
        __threadfence();  // acquire: see other blocks' topk/validn
        __shared__ int pre[Cn + 1];
        if (t == 0) {
            int acc = 0;
            for (int oc = 0; oc < Cn; ++oc) {
                pre[oc] = acc;
                acc += (int)validn[b * Cn + ((oc + 1) & 3)];  // order [1,2,3,0]
            }
            pre[Cn] = acc;
        }
        __syncthreads();
        if (t < Cn * NPTS) {  // 128 output slots for batch b
            const int j = t;
            int label = -1, z = 0, y = 0, x = 0;
            if (j < pre[Cn]) {
                int oc = 0;
                while (j >= pre[oc + 1]) ++oc;
                int c = (oc + 1) & 3;
                int r = j - pre[oc];
                uint2 e = topk[(b * Cn + c) * NPTS + r];
                int idx = (int)e.y;
                z = idx >> 14;          // idx / (128*128)
                y = (idx >> 7) & 127;   // (idx / 128) % 128
                x = idx & 127;          // idx % 128
                label = c;
            }
            int* coords = out;                       // 2*128*3 = 768 ints
            int* labels = out + Bn * Cn * NPTS * 3;  // then 2*128 = 256 ints
            int bo = b * Cn * NPTS + j;
            coords[bo * 3 + 0] = z;
            coords[bo * 3 + 1] = y;
            coords[bo * 3 + 2] = x;
            labels[bo] = label;
        }
    }
}

extern "C" void kernel_launch(void* const* d_in, const int* in_sizes, int n_in,
                              void* d_out, int out_size, void* d_ws, size_t ws_size,
                              hipStream_t stream) {
    const float* logits = (const float*)d_in[0];
    int* out = (int*)d_out;

    // Workspace layout
    unsigned int* cnt = (unsigned int*)d_ws;             // 8 u32  @0
    unsigned int* done = cnt + Bn * Cn;                  // 2 u32  @32
    unsigned int* validn = done + Bn;                    // 8 u32  @40
    uint2* topk = (uint2*)(validn + Bn * Cn);            // 8*32 uint2 @72 (8-aligned)
    uint2* cand = topk + Bn * Cn * NPTS;                 // 8 * cap uint2
    size_t fixed = (size_t)((char*)cand - (char*)d_ws);
    int cap = (int)((ws_size - fixed) / (Bn * Cn * sizeof(uint2)));
    if (cap > (1 << 18)) cap = 1 << 18;   // 256k entries/bc >> the ~18k expected
    if (cap < 4096) cap = 4096;

    // Zero cnt (8) + done (2) counters only
    hipMemsetAsync(cnt, 0, (Bn * Cn + Bn) * sizeof(unsigned int), stream);

    dim3 grid(Sn / PB, Bn);   // (512, 2) = 1024 blocks, fully co-resident at 4 blk/CU
    fused_kernel<<<grid, BT, 0, stream>>>(logits, cnt, cand, cap);
    select_emit<<<Bn * Cn, 1024, 0, stream>>>(cnt, cand, cap, validn, topk, done, out);
}